// Round 8
// baseline (1164.851 us; speedup 1.0000x reference)
//
#include <hip/hip_runtime.h>
#include <math.h>

// Problem constants (N=64, C=256, H=56, W=56, K=8)
#define NB   64
#define CB   256
#define KB   8
#define HWSZ 3136          // 49 floats/lane = 12 float4 + 1 tail
#define PLANES 16384
#define GRID 1024          // 4 blocks/CU * 256 CU
#define PPB  16            // planes per block (4 per wave: retain 3, re-read 1)
#define EPSV 1e-5f

typedef float    floatx4 __attribute__((ext_vector_type(4)));
typedef _Float16 halfx2  __attribute__((ext_vector_type(2)));

__device__ __forceinline__ halfx2 pk(float a, float b) {
    halfx2 h; h.x = (_Float16)a; h.y = (_Float16)b; return h;
}

// Fully-inlined one-shot grid barrier (counter pre-zeroed per call).
// No function-call ABI boundary -> live VGPRs stay in registers.
__device__ __forceinline__ void grid_barrier(int* cnt) {
    __threadfence();                       // release this block's writes to agent scope
    __syncthreads();
    if (threadIdx.x == 0) {
        __hip_atomic_fetch_add(cnt, 1, __ATOMIC_ACQ_REL, __HIP_MEMORY_SCOPE_AGENT);
        while (__hip_atomic_load(cnt, __ATOMIC_ACQUIRE, __HIP_MEMORY_SCOPE_AGENT) < GRID)
            __builtin_amdgcn_s_sleep(2);
    }
    __syncthreads();
}

// ---------------------------------------------------------------------------
// Persistent kernel. Phase 1: read x once, stats; retain planes 0..2 of each
// wave as fp16 in VGPRs; plane 3 re-read in phase 2.
// ---------------------------------------------------------------------------
__global__ __launch_bounds__(256, 4) void k_fused(
        const float* __restrict__ x,
        const float* __restrict__ Ww,
        const float* __restrict__ Wb,
        const float* __restrict__ alpha,
        const float* __restrict__ beta,
        float* __restrict__ out,
        float* __restrict__ xm,
        float* __restrict__ x2m,
        float* __restrict__ g,
        float* __restrict__ rstd,
        float* __restrict__ murstd,
        int* __restrict__ bar1,
        int* __restrict__ bar2) {
    __shared__ float lg[NB][KB];
    __shared__ float gs[NB][KB];

    const int tid  = threadIdx.x;
    const int wav  = tid >> 6;
    const int lane = tid & 63;
    const int blk  = blockIdx.x;
    const int p0   = blk * PPB + wav * 4;

    halfx2 d[3][12][2];   // 72 VGPRs packed fp16 (planes 0..2)
    float  tails[3];

    // ---- phase 1: retained planes 0..2 ----
    #pragma unroll
    for (int p = 0; p < 3; ++p) {
        const float* xp = x + (size_t)(p0 + p) * HWSZ;
        const floatx4* xv = (const floatx4*)xp;
        float s = 0.f, s2 = 0.f;
        #pragma unroll
        for (int i = 0; i < 12; ++i) {
            floatx4 v = __builtin_nontemporal_load(&xv[lane + 64 * i]);
            s  += v.x + v.y + v.z + v.w;
            s2 += v.x*v.x + v.y*v.y + v.z*v.z + v.w*v.w;
            d[p][i][0] = pk(v.x, v.y);
            d[p][i][1] = pk(v.z, v.w);
        }
        const float t = xp[3072 + lane];
        s += t; s2 += t * t;
        tails[p] = t;
        #pragma unroll
        for (int off = 32; off > 0; off >>= 1) {
            s  += __shfl_down(s,  off, 64);
            s2 += __shfl_down(s2, off, 64);
        }
        if (lane == 0) {
            xm[p0 + p]  = s  * (1.f / HWSZ);
            x2m[p0 + p] = s2 * (1.f / HWSZ);
        }
    }
    // ---- phase 1: plane 3 (stats only, caching loads) ----
    {
        const float* xp = x + (size_t)(p0 + 3) * HWSZ;
        const floatx4* xv = (const floatx4*)xp;
        float s = 0.f, s2 = 0.f;
        #pragma unroll
        for (int i = 0; i < 12; ++i) {
            floatx4 v = xv[lane + 64 * i];
            s  += v.x + v.y + v.z + v.w;
            s2 += v.x*v.x + v.y*v.y + v.z*v.z + v.w*v.w;
        }
        const float t = xp[3072 + lane];
        s += t; s2 += t * t;
        #pragma unroll
        for (int off = 32; off > 0; off >>= 1) {
            s  += __shfl_down(s,  off, 64);
            s2 += __shfl_down(s2, off, 64);
        }
        if (lane == 0) {
            xm[p0 + 3]  = s  * (1.f / HWSZ);
            x2m[p0 + 3] = s2 * (1.f / HWSZ);
        }
    }

    grid_barrier(bar1);

    // ---- gate phase: blocks 0..7 (one expert each) ----
    if (blk < KB) {
        for (int p = tid; p < NB * KB; p += 256) {
            const int n = p >> 3, k = p & 7;
            const float* xr = xm + n * CB;
            const float* wr = Ww + k * CB;
            float acc = 0.f;
            #pragma unroll 8
            for (int c = 0; c < CB; ++c) acc = fmaf(xr[c], wr[c], acc);
            lg[n][k] = acc + Wb[k];
        }
        __syncthreads();
        if (tid < NB) {
            float m = lg[tid][0];
            #pragma unroll
            for (int j = 1; j < KB; ++j) m = fmaxf(m, lg[tid][j]);
            float e[KB], s = 0.f;
            #pragma unroll
            for (int j = 0; j < KB; ++j) { e[j] = expf(lg[tid][j] - m); s += e[j]; }
            const float inv = 1.f / s;
            #pragma unroll
            for (int j = 0; j < KB; ++j) gs[tid][j] = e[j] * inv;
        }
        __syncthreads();
        const int k = blk, c = tid;
        float sg = 0.f, sm = 0.f, s2 = 0.f;
        #pragma unroll 8
        for (int n = 0; n < NB; ++n) {
            const float gn = gs[n][k];
            sg += gn;
            sm = fmaf(gn, xm[n * CB + c], sm);
            s2 = fmaf(gn, x2m[n * CB + c], s2);
        }
        const float inv = 1.f / sg;
        const float mu  = sm * inv;
        const float var = fmaf(-mu, mu, s2 * inv);
        const float rs  = rsqrtf(var + EPSV);
        rstd[k * CB + c]   = rs;
        murstd[k * CB + c] = mu * rs;
        if (blk == 0) {
            for (int p = tid; p < NB * KB; p += 256) g[p] = gs[p >> 3][p & 7];
        }
    }

    grid_barrier(bar2);

    // ---- phase 2: apply ----
    const int n = p0 >> 8;   // all 16 planes of this block share one n
    #pragma unroll
    for (int p = 0; p < 4; ++p) {
        const int plane = p0 + p;
        const int c = plane & 255;
        float a = 0.f, b = 0.f;
        #pragma unroll
        for (int k = 0; k < KB; ++k) {
            const float gk = g[n * KB + k];          // uniform -> scalar loads
            a = fmaf(gk, rstd[k * CB + c],   a);
            b = fmaf(gk, murstd[k * CB + c], b);
        }
        const float al = alpha[c];
        const float sc = al * a;
        const float sh = fmaf(-al, b, beta[c]);

        float* op = out + (size_t)plane * HWSZ;
        floatx4* ov = (floatx4*)op;
        if (p < 3) {
            #pragma unroll
            for (int i = 0; i < 12; ++i) {
                const halfx2 h0 = d[p][i][0];
                const halfx2 h1 = d[p][i][1];
                floatx4 r;
                r.x = fmaf((float)h0.x, sc, sh);
                r.y = fmaf((float)h0.y, sc, sh);
                r.z = fmaf((float)h1.x, sc, sh);
                r.w = fmaf((float)h1.y, sc, sh);
                __builtin_nontemporal_store(r, &ov[lane + 64 * i]);
            }
            __builtin_nontemporal_store(fmaf(tails[p], sc, sh), &op[3072 + lane]);
        } else {
            const float* xp = x + (size_t)plane * HWSZ;
            const floatx4* xv = (const floatx4*)xp;
            #pragma unroll
            for (int i = 0; i < 12; ++i) {
                floatx4 v = xv[lane + 64 * i];       // exact fp32 for this plane
                floatx4 r;
                r.x = fmaf(v.x, sc, sh);
                r.y = fmaf(v.y, sc, sh);
                r.z = fmaf(v.z, sc, sh);
                r.w = fmaf(v.w, sc, sh);
                __builtin_nontemporal_store(r, &ov[lane + 64 * i]);
            }
            __builtin_nontemporal_store(fmaf(xp[3072 + lane], sc, sh), &op[3072 + lane]);
        }
    }
}

// ======================= fallback path (proven R3) =========================
__global__ __launch_bounds__(256) void k_stats(const float* __restrict__ x,
                                               float* __restrict__ xm,
                                               float* __restrict__ x2m) {
    const int plane = blockIdx.x;
    const floatx4* xp = (const floatx4*)(x + (size_t)plane * HWSZ);
    float s = 0.f, s2 = 0.f;
    for (int i = threadIdx.x; i < 784; i += 256) {
        floatx4 v = xp[i];
        s  += v.x + v.y + v.z + v.w;
        s2 += v.x*v.x + v.y*v.y + v.z*v.z + v.w*v.w;
    }
    #pragma unroll
    for (int off = 32; off > 0; off >>= 1) {
        s  += __shfl_down(s,  off, 64);
        s2 += __shfl_down(s2, off, 64);
    }
    __shared__ float ls[4], ls2[4];
    const int lane = threadIdx.x & 63, w = threadIdx.x >> 6;
    if (lane == 0) { ls[w] = s; ls2[w] = s2; }
    __syncthreads();
    if (threadIdx.x == 0) {
        xm[plane]  = (ls[0]+ls[1]+ls[2]+ls[3]) * (1.f / HWSZ);
        x2m[plane] = (ls2[0]+ls2[1]+ls2[2]+ls2[3]) * (1.f / HWSZ);
    }
}

__global__ __launch_bounds__(256) void k_gate8(const float* __restrict__ xm,
                                               const float* __restrict__ x2m,
                                               const float* __restrict__ Ww,
                                               const float* __restrict__ Wb,
                                               float* __restrict__ g,
                                               float* __restrict__ rstd,
                                               float* __restrict__ murstd) {
    __shared__ float lg[NB][KB];
    __shared__ float gs[NB][KB];
    const int tid = threadIdx.x;
    for (int p = tid; p < NB * KB; p += 256) {
        const int n = p >> 3, k = p & 7;
        const float* xr = xm + n * CB;
        const float* wr = Ww + k * CB;
        float acc = 0.f;
        #pragma unroll 8
        for (int c = 0; c < CB; ++c) acc = fmaf(xr[c], wr[c], acc);
        lg[n][k] = acc + Wb[k];
    }
    __syncthreads();
    if (tid < NB) {
        float m = lg[tid][0];
        #pragma unroll
        for (int j = 1; j < KB; ++j) m = fmaxf(m, lg[tid][j]);
        float e[KB], s = 0.f;
        #pragma unroll
        for (int j = 0; j < KB; ++j) { e[j] = expf(lg[tid][j] - m); s += e[j]; }
        const float inv = 1.f / s;
        #pragma unroll
        for (int j = 0; j < KB; ++j) gs[tid][j] = e[j] * inv;
    }
    __syncthreads();
    const int k = blockIdx.x, c = tid;
    float sg = 0.f, sm = 0.f, s2 = 0.f;
    #pragma unroll 8
    for (int n = 0; n < NB; ++n) {
        const float gn = gs[n][k];
        sg += gn;
        sm = fmaf(gn, xm[n * CB + c], sm);
        s2 = fmaf(gn, x2m[n * CB + c], s2);
    }
    const float inv = 1.f / sg;
    const float mu  = sm * inv;
    const float var = fmaf(-mu, mu, s2 * inv);
    const float rs  = rsqrtf(var + EPSV);
    rstd[k * CB + c]   = rs;
    murstd[k * CB + c] = mu * rs;
    if (blockIdx.x == 0)
        for (int p = tid; p < NB * KB; p += 256) g[p] = gs[p >> 3][p & 7];
}

__global__ __launch_bounds__(256) void k_apply(const float* __restrict__ x,
                                               const float* __restrict__ g,
                                               const float* __restrict__ rstd,
                                               const float* __restrict__ murstd,
                                               const float* __restrict__ alpha,
                                               const float* __restrict__ beta,
                                               float* __restrict__ out) {
    const int plane = blockIdx.x;
    const int n = plane >> 8, c = plane & 255;
    float a = 0.f, b = 0.f;
    #pragma unroll
    for (int k = 0; k < KB; ++k) {
        const float gk = g[n * KB + k];
        a = fmaf(gk, rstd[k * CB + c],   a);
        b = fmaf(gk, murstd[k * CB + c], b);
    }
    const float al = alpha[c];
    const float sc = al * a;
    const float sh = fmaf(-al, b, beta[c]);
    const floatx4* xp = (const floatx4*)(x + (size_t)plane * HWSZ);
    floatx4* op = (floatx4*)(out + (size_t)plane * HWSZ);
    for (int i = threadIdx.x; i < 784; i += 256) {
        floatx4 v = xp[i];
        floatx4 r;
        r.x = fmaf(v.x, sc, sh);
        r.y = fmaf(v.y, sc, sh);
        r.z = fmaf(v.z, sc, sh);
        r.w = fmaf(v.w, sc, sh);
        __builtin_nontemporal_store(r, &op[i]);
    }
}

extern "C" void kernel_launch(void* const* d_in, const int* in_sizes, int n_in,
                              void* d_out, int out_size, void* d_ws, size_t ws_size,
                              hipStream_t stream) {
    const float* x     = (const float*)d_in[0];
    const float* Ww    = (const float*)d_in[1];
    const float* Wb    = (const float*)d_in[2];
    const float* alpha = (const float*)d_in[3];
    const float* beta  = (const float*)d_in[4];
    float* out = (float*)d_out;

    float* ws     = (float*)d_ws;
    float* xm     = ws;                       // [16384]
    float* x2m    = ws + PLANES;              // [16384]
    float* g      = ws + 2 * PLANES;          // [512]
    float* rstd   = g + NB * KB;              // [2048]
    float* murstd = rstd + KB * CB;           // [2048]
    int*   bar1   = (int*)(ws + 40960);       // 8-byte-aligned counters
    int*   bar2   = bar1 + 1;

    // zero the one-shot barrier counters (captured as a graph node)
    hipMemsetAsync(bar1, 0, 2 * sizeof(int), stream);

    void* args[] = {(void*)&x, (void*)&Ww, (void*)&Wb, (void*)&alpha, (void*)&beta,
                    (void*)&out, (void*)&xm, (void*)&x2m, (void*)&g, (void*)&rstd,
                    (void*)&murstd, (void*)&bar1, (void*)&bar2};
    hipError_t err = hipLaunchCooperativeKernel((const void*)k_fused, dim3(GRID),
                                                dim3(256), args, 0, stream);
    if (err != hipSuccess) {
        (void)hipGetLastError();   // clear sticky error, take the proven path
        k_stats <<<PLANES, 256, 0, stream>>>(x, xm, x2m);
        k_gate8 <<<KB,     256, 0, stream>>>(xm, x2m, Ww, Wb, g, rstd, murstd);
        k_apply <<<PLANES, 256, 0, stream>>>(x, g, rstd, murstd, alpha, beta, out);
    }
}

// Round 9
// 411.640 us; speedup vs baseline: 2.8298x; 2.8298x over previous
//
#include <hip/hip_runtime.h>
#include <math.h>

// Problem constants (N=64, C=256, H=56, W=56, K=8)
#define NB   64
#define CB   256
#define KB   8
#define HWSZ 3136          // 784 float4 = 12*64 chunks + 16 extra chunks -> 12 chunks/lane + 1 scalar tail/lane
#define PLANES 16384
#define GRID 1024          // 4 blocks/CU * 256 CU, exactly co-resident
#define EPSV 1e-5f
#define RET1 5             // plane-1 chunk-iterations retained (i < 5 -> 1280 elems)
#define RETW 4416          // retained halves per wave: 3136 (plane0) + 1280 (plane1 prefix)

typedef float    floatx4 __attribute__((ext_vector_type(4)));
typedef _Float16 halfx4  __attribute__((ext_vector_type(4)));

// ---------------------------------------------------------------------------
// Persistent cooperative kernel, single inline grid barrier.
// Phase 1: read x once, per-plane stats; retain plane0 + 5/12 of plane1 of
//          each wave as fp16 in LDS (spill-proof on-chip storage).
// Barrier. Gates computed block-redundantly (tiny). Phase 2: apply; retained
// part from LDS, rest re-read from HBM; nt-stores for out.
// ---------------------------------------------------------------------------
__global__ __launch_bounds__(256, 4) void k_fused(
        const float* __restrict__ x,
        const float* __restrict__ Ww,
        const float* __restrict__ Wb,
        const float* __restrict__ alpha,
        const float* __restrict__ beta,
        float* __restrict__ out,
        float* __restrict__ xm,
        float* __restrict__ x2m,
        int* __restrict__ bar) {
    __shared__ _Float16 keep[4][RETW];        // 35,328 B retention
    __shared__ float lg[NB][KB];              // logits -> gates (in place), 2 KB
    __shared__ float krs[KB][16];             // rstd for this block's channels
    __shared__ float kmrs[KB][16];            // mu*rstd
    __shared__ float scv[16], shv[16];        // per-channel scale/shift

    const int tid  = threadIdx.x;
    const int wav  = tid >> 6;
    const int lane = tid & 63;
    const int blk  = blockIdx.x;
    const int p0   = blk * 16 + wav * 4;      // wave's first plane
    const int nblk = blk >> 4;                // block's n  (16 blocks per n)
    const int c0   = (blk * 16) & 255;        // block's first channel

    // ---------------- phase 1: stats + retention ----------------
    #pragma unroll
    for (int p = 0; p < 4; ++p) {
        const float* xp = x + (size_t)(p0 + p) * HWSZ;
        const floatx4* xv = (const floatx4*)xp;
        float s = 0.f, s2 = 0.f;
        if (p == 0) {
            #pragma unroll
            for (int i = 0; i < 12; ++i) {
                floatx4 v = __builtin_nontemporal_load(&xv[lane + 64 * i]);
                s  += v.x + v.y + v.z + v.w;
                s2 += v.x*v.x + v.y*v.y + v.z*v.z + v.w*v.w;
                halfx4 h;
                h.x = (_Float16)v.x; h.y = (_Float16)v.y;
                h.z = (_Float16)v.z; h.w = (_Float16)v.w;
                *(halfx4*)&keep[wav][4 * (i * 64 + lane)] = h;
            }
            const float t = __builtin_nontemporal_load(&xp[3072 + lane]);
            s += t; s2 += t * t;
            keep[wav][3072 + lane] = (_Float16)t;
        } else if (p == 1) {
            #pragma unroll
            for (int i = 0; i < 12; ++i) {
                floatx4 v;
                if (i < RET1) {
                    v = __builtin_nontemporal_load(&xv[lane + 64 * i]);
                    halfx4 h;
                    h.x = (_Float16)v.x; h.y = (_Float16)v.y;
                    h.z = (_Float16)v.z; h.w = (_Float16)v.w;
                    *(halfx4*)&keep[wav][3136 + 4 * (i * 64 + lane)] = h;
                } else {
                    v = xv[lane + 64 * i];    // caching: may linger in L3
                }
                s  += v.x + v.y + v.z + v.w;
                s2 += v.x*v.x + v.y*v.y + v.z*v.z + v.w*v.w;
            }
            const float t = xp[3072 + lane];
            s += t; s2 += t * t;
        } else {
            #pragma unroll
            for (int i = 0; i < 12; ++i) {
                floatx4 v = xv[lane + 64 * i];
                s  += v.x + v.y + v.z + v.w;
                s2 += v.x*v.x + v.y*v.y + v.z*v.z + v.w*v.w;
            }
            const float t = xp[3072 + lane];
            s += t; s2 += t * t;
        }
        #pragma unroll
        for (int off = 32; off > 0; off >>= 1) {
            s  += __shfl_down(s,  off, 64);
            s2 += __shfl_down(s2, off, 64);
        }
        if (lane == 0) {
            xm[p0 + p]  = s  * (1.f / HWSZ);
            x2m[p0 + p] = s2 * (1.f / HWSZ);
        }
    }

    // ---------------- single inline grid barrier ----------------
    __threadfence();
    __syncthreads();
    if (tid == 0) {
        __hip_atomic_fetch_add(bar, 1, __ATOMIC_ACQ_REL, __HIP_MEMORY_SCOPE_AGENT);
        while (__hip_atomic_load(bar, __ATOMIC_ACQUIRE, __HIP_MEMORY_SCOPE_AGENT) < GRID)
            __builtin_amdgcn_s_sleep(2);
    }
    __syncthreads();

    // ---------------- gates: block-redundant (tiny) ----------------
    for (int p = tid; p < NB * KB; p += 256) {
        const int n = p >> 3, k = p & 7;
        const floatx4* xr = (const floatx4*)(xm + n * CB);
        const floatx4* wr = (const floatx4*)(Ww + k * CB);
        float acc = 0.f;
        #pragma unroll 8
        for (int c4 = 0; c4 < CB / 4; ++c4) {
            floatx4 a = xr[c4], w = wr[c4];
            acc = fmaf(a.x, w.x, fmaf(a.y, w.y, fmaf(a.z, w.z, fmaf(a.w, w.w, acc))));
        }
        lg[n][k] = acc + Wb[k];
    }
    __syncthreads();
    if (tid < NB) {
        float e[KB];
        float m = lg[tid][0];
        #pragma unroll
        for (int j = 1; j < KB; ++j) m = fmaxf(m, lg[tid][j]);
        float s = 0.f;
        #pragma unroll
        for (int j = 0; j < KB; ++j) { e[j] = expf(lg[tid][j] - m); s += e[j]; }
        const float inv = 1.f / s;
        #pragma unroll
        for (int j = 0; j < KB; ++j) lg[tid][j] = e[j] * inv;   // in-place gates
    }
    __syncthreads();
    if (tid < 128) {                    // (k, ci): expert stats for our 16 channels
        const int k = tid >> 4, ci = tid & 15, c = c0 + ci;
        float sg = 0.f, sm = 0.f, s2 = 0.f;
        #pragma unroll 8
        for (int n = 0; n < NB; ++n) {
            const float gn = lg[n][k];
            sg += gn;
            sm = fmaf(gn, xm[n * CB + c], sm);
            s2 = fmaf(gn, x2m[n * CB + c], s2);
        }
        const float inv = 1.f / sg;
        const float mu  = sm * inv;
        const float var = fmaf(-mu, mu, s2 * inv);
        const float rs  = rsqrtf(var + EPSV);
        krs[k][ci]  = rs;
        kmrs[k][ci] = mu * rs;
    }
    __syncthreads();
    if (tid < 16) {                     // per-channel scale/shift
        const int c = c0 + tid;
        float a = 0.f, b = 0.f;
        #pragma unroll
        for (int k = 0; k < KB; ++k) {
            const float gk = lg[nblk][k];
            a = fmaf(gk, krs[k][tid],  a);
            b = fmaf(gk, kmrs[k][tid], b);
        }
        const float al = alpha[c];
        scv[tid] = al * a;
        shv[tid] = fmaf(-al, b, beta[c]);
    }
    __syncthreads();

    // ---------------- phase 2: apply ----------------
    #pragma unroll
    for (int p = 0; p < 4; ++p) {
        const int plane = p0 + p;
        const float sc = scv[wav * 4 + p];
        const float sh = shv[wav * 4 + p];
        float* op = out + (size_t)plane * HWSZ;
        floatx4* ov = (floatx4*)op;
        if (p == 0) {
            #pragma unroll
            for (int i = 0; i < 12; ++i) {
                halfx4 h = *(halfx4*)&keep[wav][4 * (i * 64 + lane)];
                floatx4 r;
                r.x = fmaf((float)h.x, sc, sh);
                r.y = fmaf((float)h.y, sc, sh);
                r.z = fmaf((float)h.z, sc, sh);
                r.w = fmaf((float)h.w, sc, sh);
                __builtin_nontemporal_store(r, &ov[lane + 64 * i]);
            }
            __builtin_nontemporal_store(
                fmaf((float)keep[wav][3072 + lane], sc, sh), &op[3072 + lane]);
        } else if (p == 1) {
            const float* xp = x + (size_t)plane * HWSZ;
            const floatx4* xv = (const floatx4*)xp;
            #pragma unroll
            for (int i = 0; i < 12; ++i) {
                floatx4 r;
                if (i < RET1) {
                    halfx4 h = *(halfx4*)&keep[wav][3136 + 4 * (i * 64 + lane)];
                    r.x = fmaf((float)h.x, sc, sh);
                    r.y = fmaf((float)h.y, sc, sh);
                    r.z = fmaf((float)h.z, sc, sh);
                    r.w = fmaf((float)h.w, sc, sh);
                } else {
                    floatx4 v = xv[lane + 64 * i];
                    r.x = fmaf(v.x, sc, sh);
                    r.y = fmaf(v.y, sc, sh);
                    r.z = fmaf(v.z, sc, sh);
                    r.w = fmaf(v.w, sc, sh);
                }
                __builtin_nontemporal_store(r, &ov[lane + 64 * i]);
            }
            __builtin_nontemporal_store(fmaf(xp[3072 + lane], sc, sh), &op[3072 + lane]);
        } else {
            const float* xp = x + (size_t)plane * HWSZ;
            const floatx4* xv = (const floatx4*)xp;
            #pragma unroll
            for (int i = 0; i < 12; ++i) {
                floatx4 v = xv[lane + 64 * i];
                floatx4 r;
                r.x = fmaf(v.x, sc, sh);
                r.y = fmaf(v.y, sc, sh);
                r.z = fmaf(v.z, sc, sh);
                r.w = fmaf(v.w, sc, sh);
                __builtin_nontemporal_store(r, &ov[lane + 64 * i]);
            }
            __builtin_nontemporal_store(fmaf(xp[3072 + lane], sc, sh), &op[3072 + lane]);
        }
    }
}

// ======================= fallback path (proven R3) =========================
__global__ __launch_bounds__(256) void k_stats(const float* __restrict__ x,
                                               float* __restrict__ xm,
                                               float* __restrict__ x2m) {
    const int plane = blockIdx.x;
    const floatx4* xp = (const floatx4*)(x + (size_t)plane * HWSZ);
    float s = 0.f, s2 = 0.f;
    for (int i = threadIdx.x; i < 784; i += 256) {
        floatx4 v = xp[i];
        s  += v.x + v.y + v.z + v.w;
        s2 += v.x*v.x + v.y*v.y + v.z*v.z + v.w*v.w;
    }
    #pragma unroll
    for (int off = 32; off > 0; off >>= 1) {
        s  += __shfl_down(s,  off, 64);
        s2 += __shfl_down(s2, off, 64);
    }
    __shared__ float ls[4], ls2[4];
    const int lane = threadIdx.x & 63, w = threadIdx.x >> 6;
    if (lane == 0) { ls[w] = s; ls2[w] = s2; }
    __syncthreads();
    if (threadIdx.x == 0) {
        xm[plane]  = (ls[0]+ls[1]+ls[2]+ls[3]) * (1.f / HWSZ);
        x2m[plane] = (ls2[0]+ls2[1]+ls2[2]+ls2[3]) * (1.f / HWSZ);
    }
}

__global__ __launch_bounds__(256) void k_gate8(const float* __restrict__ xm,
                                               const float* __restrict__ x2m,
                                               const float* __restrict__ Ww,
                                               const float* __restrict__ Wb,
                                               float* __restrict__ g,
                                               float* __restrict__ rstd,
                                               float* __restrict__ murstd) {
    __shared__ float lg[NB][KB];
    __shared__ float gs[NB][KB];
    const int tid = threadIdx.x;
    for (int p = tid; p < NB * KB; p += 256) {
        const int n = p >> 3, k = p & 7;
        const float* xr = xm + n * CB;
        const float* wr = Ww + k * CB;
        float acc = 0.f;
        #pragma unroll 8
        for (int c = 0; c < CB; ++c) acc = fmaf(xr[c], wr[c], acc);
        lg[n][k] = acc + Wb[k];
    }
    __syncthreads();
    if (tid < NB) {
        float m = lg[tid][0];
        #pragma unroll
        for (int j = 1; j < KB; ++j) m = fmaxf(m, lg[tid][j]);
        float e[KB], s = 0.f;
        #pragma unroll
        for (int j = 0; j < KB; ++j) { e[j] = expf(lg[tid][j] - m); s += e[j]; }
        const float inv = 1.f / s;
        #pragma unroll
        for (int j = 0; j < KB; ++j) gs[tid][j] = e[j] * inv;
    }
    __syncthreads();
    const int k = blockIdx.x, c = tid;
    float sg = 0.f, sm = 0.f, s2 = 0.f;
    #pragma unroll 8
    for (int n = 0; n < NB; ++n) {
        const float gn = gs[n][k];
        sg += gn;
        sm = fmaf(gn, xm[n * CB + c], sm);
        s2 = fmaf(gn, x2m[n * CB + c], s2);
    }
    const float inv = 1.f / sg;
    const float mu  = sm * inv;
    const float var = fmaf(-mu, mu, s2 * inv);
    const float rs  = rsqrtf(var + EPSV);
    rstd[k * CB + c]   = rs;
    murstd[k * CB + c] = mu * rs;
    if (blockIdx.x == 0)
        for (int p = tid; p < NB * KB; p += 256) g[p] = gs[p >> 3][p & 7];
}

__global__ __launch_bounds__(256) void k_apply(const float* __restrict__ x,
                                               const float* __restrict__ g,
                                               const float* __restrict__ rstd,
                                               const float* __restrict__ murstd,
                                               const float* __restrict__ alpha,
                                               const float* __restrict__ beta,
                                               float* __restrict__ out) {
    const int plane = blockIdx.x;
    const int n = plane >> 8, c = plane & 255;
    float a = 0.f, b = 0.f;
    #pragma unroll
    for (int k = 0; k < KB; ++k) {
        const float gk = g[n * KB + k];
        a = fmaf(gk, rstd[k * CB + c],   a);
        b = fmaf(gk, murstd[k * CB + c], b);
    }
    const float al = alpha[c];
    const float sc = al * a;
    const float sh = fmaf(-al, b, beta[c]);
    const floatx4* xp = (const floatx4*)(x + (size_t)plane * HWSZ);
    floatx4* op = (floatx4*)(out + (size_t)plane * HWSZ);
    for (int i = threadIdx.x; i < 784; i += 256) {
        floatx4 v = xp[i];
        floatx4 r;
        r.x = fmaf(v.x, sc, sh);
        r.y = fmaf(v.y, sc, sh);
        r.z = fmaf(v.z, sc, sh);
        r.w = fmaf(v.w, sc, sh);
        __builtin_nontemporal_store(r, &op[i]);
    }
}

extern "C" void kernel_launch(void* const* d_in, const int* in_sizes, int n_in,
                              void* d_out, int out_size, void* d_ws, size_t ws_size,
                              hipStream_t stream) {
    const float* x     = (const float*)d_in[0];
    const float* Ww    = (const float*)d_in[1];
    const float* Wb    = (const float*)d_in[2];
    const float* alpha = (const float*)d_in[3];
    const float* beta  = (const float*)d_in[4];
    float* out = (float*)d_out;

    float* ws  = (float*)d_ws;
    float* xm  = ws;                          // [16384]
    float* x2m = ws + PLANES;                 // [16384]
    int*   bar = (int*)(ws + 2 * PLANES);     // 1 int, zeroed per call
    // fallback-only buffers
    float* g      = ws + 2 * PLANES + 64;     // [512]
    float* rstd   = g + NB * KB;              // [2048]
    float* murstd = rstd + KB * CB;           // [2048]

    hipMemsetAsync(bar, 0, sizeof(int), stream);

    void* args[] = {(void*)&x, (void*)&Ww, (void*)&Wb, (void*)&alpha, (void*)&beta,
                    (void*)&out, (void*)&xm, (void*)&x2m, (void*)&bar};
    hipError_t err = hipLaunchCooperativeKernel((const void*)k_fused, dim3(GRID),
                                                dim3(256), args, 0, stream);
    if (err != hipSuccess) {
        (void)hipGetLastError();   // clear sticky error, take the proven path
        k_stats <<<PLANES, 256, 0, stream>>>(x, xm, x2m);
        k_gate8 <<<KB,     256, 0, stream>>>(xm, x2m, Ww, Wb, g, rstd, murstd);
        k_apply <<<PLANES, 256, 0, stream>>>(x, g, rstd, murstd, alpha, beta, out);
    }
}

// Round 10
// 117.441 us; speedup vs baseline: 9.9186x; 3.5051x over previous
//
#include <hip/hip_runtime.h>
#include <math.h>

// Problem constants (N=64, C=256, H=56, W=56, K=8)
#define NB   64
#define CB   256
#define KB   8
#define HWSZ 3136          // per lane: 12 float4 + 1 tail float
#define PLANES 16384
#define EPSV 1e-5f

typedef float floatx4 __attribute__((ext_vector_type(4)));

// ---------------------------------------------------------------------------
// Kernel 1: per-(n,c) spatial mean / mean-of-squares.
// One WAVE per plane (4 waves / 256-thread block): lane reads xv[lane+64*i],
// i<12, plus scalar tail; pure shuffle reduce — no LDS, no __syncthreads.
// Regular loads: x allocates in L3 (any later hit in k_apply is free).
// ---------------------------------------------------------------------------
__global__ __launch_bounds__(256) void k_stats(const float* __restrict__ x,
                                               float* __restrict__ xm,
                                               float* __restrict__ x2m) {
    const int wav   = threadIdx.x >> 6;
    const int lane  = threadIdx.x & 63;
    const int plane = blockIdx.x * 4 + wav;

    const float* xp = x + (size_t)plane * HWSZ;
    const floatx4* xv = (const floatx4*)xp;

    float s = 0.f, s2 = 0.f;
    #pragma unroll
    for (int i = 0; i < 12; ++i) {
        floatx4 v = xv[lane + 64 * i];
        s  += v.x + v.y + v.z + v.w;
        s2 += v.x*v.x + v.y*v.y + v.z*v.z + v.w*v.w;
    }
    const float t = xp[3072 + lane];
    s += t; s2 += t * t;

    #pragma unroll
    for (int off = 32; off > 0; off >>= 1) {
        s  += __shfl_down(s,  off, 64);
        s2 += __shfl_down(s2, off, 64);
    }
    if (lane == 0) {
        xm[plane]  = s  * (1.f / HWSZ);
        x2m[plane] = s2 * (1.f / HWSZ);
    }
}

// ---------------------------------------------------------------------------
// Kernel 2: 8 blocks (one per expert). Each block redundantly computes the
// gate matrix (logits + softmax, tiny), then its expert's weighted mean/rstd
// per channel. Block 0 publishes g.  (Proven in R3.)
// ---------------------------------------------------------------------------
__global__ __launch_bounds__(256) void k_gate8(const float* __restrict__ xm,
                                               const float* __restrict__ x2m,
                                               const float* __restrict__ Ww,
                                               const float* __restrict__ Wb,
                                               float* __restrict__ g,        // [N*K]
                                               float* __restrict__ rstd,     // [K*C]
                                               float* __restrict__ murstd) { // [K*C]
    __shared__ float lg[NB][KB];
    __shared__ float gs[NB][KB];
    const int tid = threadIdx.x;

    for (int p = tid; p < NB * KB; p += 256) {
        const int n = p >> 3, k = p & 7;
        const floatx4* xr = (const floatx4*)(xm + n * CB);
        const floatx4* wr = (const floatx4*)(Ww + k * CB);
        float acc = 0.f;
        #pragma unroll 8
        for (int c4 = 0; c4 < CB / 4; ++c4) {
            floatx4 a = xr[c4], w = wr[c4];
            acc = fmaf(a.x, w.x, fmaf(a.y, w.y, fmaf(a.z, w.z, fmaf(a.w, w.w, acc))));
        }
        lg[n][k] = acc + Wb[k];
    }
    __syncthreads();
    if (tid < NB) {
        float m = lg[tid][0];
        #pragma unroll
        for (int j = 1; j < KB; ++j) m = fmaxf(m, lg[tid][j]);
        float e[KB], s = 0.f;
        #pragma unroll
        for (int j = 0; j < KB; ++j) { e[j] = expf(lg[tid][j] - m); s += e[j]; }
        const float inv = 1.f / s;
        #pragma unroll
        for (int j = 0; j < KB; ++j) gs[tid][j] = e[j] * inv;
    }
    __syncthreads();
    const int k = blockIdx.x, c = tid;
    float sg = 0.f, sm = 0.f, s2 = 0.f;
    #pragma unroll 8
    for (int n = 0; n < NB; ++n) {
        const float gn = gs[n][k];
        sg += gn;
        sm = fmaf(gn, xm[n * CB + c], sm);
        s2 = fmaf(gn, x2m[n * CB + c], s2);
    }
    const float inv = 1.f / sg;
    const float mu  = sm * inv;
    const float var = fmaf(-mu, mu, s2 * inv);
    const float rs  = rsqrtf(var + EPSV);
    rstd[k * CB + c]   = rs;
    murstd[k * CB + c] = mu * rs;
    if (blockIdx.x == 0)
        for (int p = tid; p < NB * KB; p += 256) g[p] = gs[p >> 3][p & 7];
}

// ---------------------------------------------------------------------------
// Kernel 3: out = x*scale + shift. One WAVE per plane; scale/shift from
// wave-uniform scalar loads; fully-coalesced 1KB stores, non-temporal.
// ---------------------------------------------------------------------------
__global__ __launch_bounds__(256) void k_apply(const float* __restrict__ x,
                                               const float* __restrict__ g,
                                               const float* __restrict__ rstd,
                                               const float* __restrict__ murstd,
                                               const float* __restrict__ alpha,
                                               const float* __restrict__ beta,
                                               float* __restrict__ out) {
    const int wav   = threadIdx.x >> 6;
    const int lane  = threadIdx.x & 63;
    const int plane = blockIdx.x * 4 + wav;
    const int n = plane >> 8, c = plane & 255;

    float a = 0.f, b = 0.f;
    #pragma unroll
    for (int k = 0; k < KB; ++k) {
        const float gk = g[n * KB + k];        // wave-uniform -> s_loads
        a = fmaf(gk, rstd[k * CB + c],   a);
        b = fmaf(gk, murstd[k * CB + c], b);
    }
    const float al = alpha[c];
    const float sc = al * a;
    const float sh = fmaf(-al, b, beta[c]);

    const float* xp = x + (size_t)plane * HWSZ;
    const floatx4* xv = (const floatx4*)xp;
    float* op = out + (size_t)plane * HWSZ;
    floatx4* ov = (floatx4*)op;

    #pragma unroll
    for (int i = 0; i < 12; ++i) {
        floatx4 v = xv[lane + 64 * i];
        floatx4 r;
        r.x = fmaf(v.x, sc, sh);
        r.y = fmaf(v.y, sc, sh);
        r.z = fmaf(v.z, sc, sh);
        r.w = fmaf(v.w, sc, sh);
        __builtin_nontemporal_store(r, &ov[lane + 64 * i]);
    }
    __builtin_nontemporal_store(fmaf(xp[3072 + lane], sc, sh), &op[3072 + lane]);
}

extern "C" void kernel_launch(void* const* d_in, const int* in_sizes, int n_in,
                              void* d_out, int out_size, void* d_ws, size_t ws_size,
                              hipStream_t stream) {
    const float* x     = (const float*)d_in[0];
    const float* Ww    = (const float*)d_in[1];
    const float* Wb    = (const float*)d_in[2];
    const float* alpha = (const float*)d_in[3];
    const float* beta  = (const float*)d_in[4];
    float* out = (float*)d_out;

    float* ws     = (float*)d_ws;
    float* xm     = ws;                      // [16384]
    float* x2m    = ws + PLANES;             // [16384]
    float* g      = ws + 2 * PLANES;         // [512]
    float* rstd   = g + NB * KB;             // [2048]
    float* murstd = rstd + KB * CB;          // [2048]

    k_stats <<<PLANES / 4, 256, 0, stream>>>(x, xm, x2m);
    k_gate8 <<<KB,         256, 0, stream>>>(xm, x2m, Ww, Wb, g, rstd, murstd);
    k_apply <<<PLANES / 4, 256, 0, stream>>>(x, g, rstd, murstd, alpha, beta, out);
}